// Round 1
// baseline (217.604 us; speedup 1.0000x reference)
//
#include <hip/hip_runtime.h>

// IDM layer forward: 1M independent elements, 50 Euler steps each,
// output (BATCH, 50) f32 row-major. Write-BW-bound (200 MB out, 12 MB in).
//
// Structure: 1 thread = 1 element. All 50 ahat values computed in registers
// (fully unrolled -> static indexing, no scratch). Staged to LDS in the
// identity layout lds[e*50+t] == block's output chunk, then streamed to
// global with linear coalesced float4 stores.

namespace {

constexpr int STEPS = 50;
constexpr int BLOCK = 256;
constexpr float DT  = 0.1f;
constexpr float EPS = 1e-5f;

__global__ __launch_bounds__(BLOCK) void idm_forward(
    const float* __restrict__ vi_in,
    const float* __restrict__ dv_in,
    const float* __restrict__ dd_in,
    const float* __restrict__ p_vf,
    const float* __restrict__ p_A,
    const float* __restrict__ p_b,
    const float* __restrict__ p_s0,
    const float* __restrict__ p_T,
    float* __restrict__ out,
    int n)
{
    __shared__ __align__(16) float lds[BLOCK * STEPS];  // 51200 B

    const int tid  = threadIdx.x;
    const int base = blockIdx.x * BLOCK;
    const int i    = base + tid;

    // Scalar learned params (single-element arrays).
    const float vf = p_vf[0];
    const float A  = p_A[0];
    const float b  = p_b[0];
    const float s0 = p_s0[0];
    const float T  = p_T[0];
    const float inv2   = 1.0f / (2.0f * sqrtf(A * b));   // 1/(2*sqrt(A*b))
    const float inv_vf = 1.0f / vf;

    float v = 0.0f, dv = 0.0f, inv_dd = 1.0f;
    if (i < n) {
        v      = vi_in[i];
        dv     = dv_in[i];
        inv_dd = 1.0f / (dd_in[i] + EPS);  // hoisted: per-step div -> mul
    }

    float acc[STEPS];
#pragma unroll
    for (int t = 0; t < STEPS; ++t) {
        // s_star = s0 + max(0, v*T + v*dv*inv2)
        const float s_star = s0 + fmaxf(0.0f, fmaf(v * dv, inv2, v * T));
        const float q  = s_star * inv_dd;        // s_star / (dd + eps)
        const float r  = v * inv_vf;             // v / vf
        const float r2 = r * r;
        const float r4 = r2 * r2;
        const float ahat = A * (1.0f - r4 - q * q);
        acc[t] = ahat;                           // recorded pre-update (scan semantics)
        v  = fmaf(ahat,  DT, v);
        dv = fmaf(ahat, -DT, dv);
    }

    // Stage to LDS: identity layout, lds[e*STEPS + t] == out[base*STEPS + ...].
    // b64 writes (t even -> 8B aligned). ~4-way bank conflict, small phase.
#pragma unroll
    for (int t = 0; t < STEPS; t += 2) {
        *reinterpret_cast<float2*>(&lds[tid * STEPS + t]) =
            make_float2(acc[t], acc[t + 1]);
    }
    __syncthreads();

    // Cooperative, fully-coalesced float4 stream-out of the block's chunk.
    const long long out_base = (long long)base * STEPS;
    const long long total    = (long long)n * STEPS;
    int chunk = BLOCK * STEPS;
    if (out_base + chunk > total) chunk = (int)(total - out_base);

    float4* __restrict__ outv      = reinterpret_cast<float4*>(out + out_base);
    const float4* __restrict__ ldv = reinterpret_cast<const float4*>(lds);
    const int nv = chunk >> 2;
    for (int m = tid; m < nv; m += BLOCK) {
        outv[m] = ldv[m];
    }
    // Scalar tail (only if valid-elem count makes chunk not /4; not hit at 1M).
    for (int k = (nv << 2) + tid; k < chunk; k += BLOCK) {
        out[out_base + k] = lds[k];
    }
}

} // namespace

extern "C" void kernel_launch(void* const* d_in, const int* in_sizes, int n_in,
                              void* d_out, int out_size, void* d_ws, size_t ws_size,
                              hipStream_t stream) {
    const float* vi = (const float*)d_in[0];
    const float* dv = (const float*)d_in[1];
    const float* dd = (const float*)d_in[2];
    const float* vf = (const float*)d_in[3];
    const float* A  = (const float*)d_in[4];
    const float* b  = (const float*)d_in[5];
    const float* s0 = (const float*)d_in[6];
    const float* T  = (const float*)d_in[7];
    float* out = (float*)d_out;

    const int n    = in_sizes[0];
    const int grid = (n + BLOCK - 1) / BLOCK;
    idm_forward<<<grid, BLOCK, 0, stream>>>(vi, dv, dd, vf, A, b, s0, T, out, n);
}